// Round 11
// baseline (3273.561 us; speedup 1.0000x reference)
//
#include <hip/hip_runtime.h>
#include <math.h>

#define SQ3F   1.7320508075688772f
#define SQRT8F 2.8284271247461903f
#define OSCALE (1.0f / 128.0f)   // (1/sqrt(64)) * (1/AVG=16)

__device__ __forceinline__ float fast_silu(float x) {
    return x * __builtin_amdgcn_rcpf(1.0f + __expf(-x));
}

// ---------------------------------------------------------------- transpose w2
__global__ __launch_bounds__(256) void tr_kernel(const float* __restrict__ w2,
                                                 float* __restrict__ w2t) {
    const int t = blockIdx.x * 256 + threadIdx.x;   // 8192 = 128 x 64
    if (t < 8192) {
        const int o = t >> 6, i = t & 63;
        w2t[t] = w2[i * 128 + o];                   // w2t[o][i] = w2[i][o]
    }
}

// ---------------------------------------------------------------- up-projection
// xall[n][m] = float4{ xs[n][m], xv[n][m][0], xv[n][m][1], xv[n][m][2] }
__global__ __launch_bounds__(256) void up_kernel(const float* __restrict__ nf,
                                                 const float* __restrict__ Wu0,
                                                 const float* __restrict__ Wu1,
                                                 float* __restrict__ xall, int N) {
    __shared__ float sW0[1024], sW1[1024];
    for (int i = threadIdx.x; i < 1024; i += 256) { sW0[i] = Wu0[i]; sW1[i] = Wu1[i]; }
    __syncthreads();
    const int t = blockIdx.x * 256 + threadIdx.x;
    const int n = t >> 5, k = t & 31;
    if (n >= N) return;
    const float* row = nf + (size_t)n * 128;
    float a0 = 0.f, a1 = 0.f, a2 = 0.f, a3 = 0.f;
#pragma unroll
    for (int m = 0; m < 32; ++m) {
        const float wa = sW0[m * 32 + k], wb = sW1[m * 32 + k];
        a0 += row[m] * wa;
        a1 += row[32 + m * 3 + 0] * wb;
        a2 += row[32 + m * 3 + 1] * wb;
        a3 += row[32 + m * 3 + 2] * wb;
    }
    const float s = 0.17677669529663687f;  // 1/sqrt(32)
    float4 o; o.x = a0 * s; o.y = a1 * s; o.z = a2 * s; o.w = a3 * s;
    reinterpret_cast<float4*>(xall)[(size_t)n * 32 + k] = o;
}

// ---------------------------------------------------------------- CSR build
__global__ __launch_bounds__(256) void hist_kernel(const int* __restrict__ rcv,
                                                   int* __restrict__ cnt, int E) {
    const int t = blockIdx.x * 256 + threadIdx.x;
    if (t < E) atomicAdd(&cnt[rcv[t]], 1);
}

__global__ __launch_bounds__(1024) void scan_kernel(const int* __restrict__ cnt,
                                                    int* __restrict__ off, int N, int E) {
    __shared__ int part[1024];
    const int t = threadIdx.x;
    const int CH = (N + 1023) / 1024;
    const int lo = t * CH;
    const int hi = (lo + CH < N) ? lo + CH : N;
    int s = 0;
    for (int i = lo; i < hi; ++i) s += cnt[i];
    part[t] = s;
    __syncthreads();
    for (int d = 1; d < 1024; d <<= 1) {
        const int v = (t >= d) ? part[t - d] : 0;
        __syncthreads();
        part[t] += v;
        __syncthreads();
    }
    int run = (t > 0) ? part[t - 1] : 0;
    for (int i = lo; i < hi; ++i) { off[i] = run; run += cnt[i]; }
    if (t == 0) off[N] = E;
}

__global__ __launch_bounds__(256) void scat_kernel(const int* __restrict__ rcv,
                                                   const int* __restrict__ off,
                                                   int* __restrict__ cur,
                                                   int* __restrict__ sid, int E) {
    const int t = blockIdx.x * 256 + threadIdx.x;
    if (t < E) {
        const int r = rcv[t];
        const int p = off[r] + atomicAdd(&cur[r], 1);
        sid[p] = t;
    }
}

// ---------------------------------------------------------------- wave->node assignment
__global__ __launch_bounds__(256) void wassign_kernel(const int* __restrict__ off,
                                                      int* __restrict__ wlo,
                                                      int* __restrict__ whi,
                                                      int N, int NW) {
    const int n = blockIdx.x * 256 + threadIdx.x;
    if (n < N) {
        int w = off[n] >> 6;
        if (w >= NW) w = NW - 1;
        atomicMin(&wlo[w], n);
        atomicMax(&whi[w], n);
    }
}

// ---------------------------------------------------------------- edge kernel v5
// ek4 + : h1 kept in REGISTERS (layer-2 fully unrolled, static indices only),
// two-pass W_out contraction to cap live VGPRs (~180), LDS used only for
// output restage + rcvt. No LDS in any hot dot-product loop.
__global__ __launch_bounds__(64, 2) void ek5(const float* __restrict__ edge_vec,
                                             const float* __restrict__ edge_len,
                                             const int*  __restrict__ senders,
                                             const int*  __restrict__ receivers,
                                             const int*  __restrict__ sid,
                                             const int*  __restrict__ off,
                                             const int*  __restrict__ wlo,
                                             const int*  __restrict__ whi,
                                             const float* __restrict__ w0,   // (8,64)
                                             const float* __restrict__ b0,   // 64
                                             const float* __restrict__ w1,   // (64,64)
                                             const float* __restrict__ b1,   // 64
                                             const float* __restrict__ b2,   // 128
                                             const float* __restrict__ w2t,  // (128,64)
                                             const float* __restrict__ Wo0,  // (64,32)
                                             const float* __restrict__ Wo1,  // (64,32)
                                             const float4* __restrict__ xall,
                                             float* __restrict__ outp,       // N x 128 (zeroed)
                                             int E) {
    __shared__ float st[64][65];                    // restage only (16.6 KiB)
    __shared__ int   rcvt[64];
    const int lane = threadIdx.x;
    const int w = blockIdx.x;
    const int nlo = wlo[w], nhi = whi[w];
    if (nhi < nlo) return;
    const int estart = off[nlo], eend = off[nhi + 1];
    if (estart >= eend) return;

    int   rprev = -1;
    float accA = 0.f, accB = 0.f;

    for (int bs = estart; bs < eend; bs += 64) {
        const int nv = (eend - bs < 64) ? (eend - bs) : 64;   // wave-uniform
        const int sp = (lane < nv) ? (bs + lane) : (eend - 1);
        const int e  = sid[sp];
        rcvt[lane] = receivers[e];

        const float ev0 = edge_vec[e * 3 + 0];
        const float ev1 = edge_vec[e * 3 + 1];
        const float ev2 = edge_vec[e * 3 + 2];
        const float r   = edge_len[e];
        const int  snd  = senders[e];

        const float nrm = sqrtf(ev0 * ev0 + ev1 * ev1 + ev2 * ev2) + 1e-12f;
        const float sc  = SQ3F * __builtin_amdgcn_rcpf(nrm);
        const float Y0 = ev0 * sc, Y1 = ev1 * sc, Y2 = ev2 * sc;

        const float xcl  = fminf(fmaxf(r, 0.0f), 1.0f);
        const float gate = (r <= 1.0f) ? SQRT8F : 0.0f;
        float emb[8];
#pragma unroll
        for (int i = 0; i < 8; ++i) {
            const float d = xcl * 7.0f - (float)i;
            emb[i] = __expf(-0.5f * d * d) * gate;
        }

        // layer 1: 8 -> 64, h0 in regs (static unroll)
        float h0[64];
#pragma unroll
        for (int o = 0; o < 64; ++o) {
            float a = b0[o];
#pragma unroll
            for (int i = 0; i < 8; ++i) a += emb[i] * w0[i * 64 + o];
            h0[o] = fast_silu(a);
        }

        // layer 2: 64 -> 64, h1 in REGS (ob fully unrolled -> static h1 index)
        float h1[64];
#pragma unroll
        for (int ob = 0; ob < 64; ob += 8) {
            float a[8];
#pragma unroll
            for (int u = 0; u < 8; ++u) a[u] = b1[ob + u];
#pragma unroll
            for (int i = 0; i < 64; ++i) {
                const float hv = h0[i];
#pragma unroll
                for (int u = 0; u < 8; ++u) a[u] += hv * w1[i * 64 + ob + u];
            }
#pragma unroll
            for (int u = 0; u < 8; ++u) h1[ob + u] = fast_silu(a[u]);
        }
        // h0 dead from here

        const float4* xrow = xall + (size_t)snd * 32;

        // ---- pass A: outS (m0,m3 paths) and tA (m1 coefficient) ----
        float outS[32], tA[32];
#pragma unroll
        for (int k = 0; k < 32; ++k) { outS[k] = 0.f; tA[k] = 0.f; }

#pragma unroll 1
        for (int m = 0; m < 32; ++m) {
            const float* r0 = w2t + m * 64;
            const float* r1 = w2t + (32 + m) * 64;
            const float* r3 = w2t + (96 + m) * 64;
            float d0 = b2[m], d1 = b2[32 + m], d3 = b2[96 + m];
#pragma unroll
            for (int i = 0; i < 64; ++i) {
                const float hv = h1[i];
                d0 += hv * r0[i]; d1 += hv * r1[i]; d3 += hv * r3[i];
            }
            const float4 g = xrow[m];
            const float ss = g.x;
            const float dv = g.y * Y0 + g.z * Y1 + g.w * Y2;
            const float a0 = d0 * ss;
            const float a3 = d3 * dv * (1.0f / SQ3F);
            const float t1 = d1 * ss;
            const float* wa = Wo0 + m * 32;
            const float* wb = Wo0 + (32 + m) * 32;
            const float* wc = Wo1 + m * 32;
#pragma unroll
            for (int k = 0; k < 32; ++k) {
                outS[k] += a0 * wa[k] + a3 * wb[k];
                tA[k]   += t1 * wc[k];
            }
        }

        // park outS in LDS rows 0..31 (frees outS before pass B)
        __syncthreads();                               // st free (prev batch done)
#pragma unroll
        for (int j = 0; j < 32; ++j) st[j][lane] = outS[j];

        // init oV from tA fold (tA dead after this)
        float oV[96];
#pragma unroll
        for (int k = 0; k < 32; ++k) {
            const float t = tA[k];
            oV[k * 3 + 0] = t * Y0;
            oV[k * 3 + 1] = t * Y1;
            oV[k * 3 + 2] = t * Y2;
        }

        // ---- pass B: oV (m2 path) ----
#pragma unroll 1
        for (int m = 0; m < 32; ++m) {
            const float* r2 = w2t + (64 + m) * 64;
            float d2 = b2[64 + m];
#pragma unroll
            for (int i = 0; i < 64; ++i) d2 += h1[i] * r2[i];
            const float4 g = xrow[m];
            const float p0 = d2 * g.y, p1 = d2 * g.z, p2 = d2 * g.w;
            const float* wd = Wo1 + (32 + m) * 32;
#pragma unroll
            for (int k = 0; k < 32; ++k) {
                const float wv = wd[k];
                oV[k * 3 + 0] += p0 * wv;
                oV[k * 3 + 1] += p1 * wv;
                oV[k * 3 + 2] += p2 * wv;
            }
        }

        // ---- chunk 0: channels 0..63 = [outS(32, already in st) | oV(0..31)] ----
#pragma unroll
        for (int j = 0; j < 32; ++j) st[32 + j][lane] = oV[j];
        __syncthreads();
        if (rprev < 0) rprev = rcvt[0];
        {
            int rA = rprev; float a = accA;
            for (int ee = 0; ee < nv; ++ee) {
                const int rc = rcvt[ee];                // wave-uniform
                if (rc != rA) {                         // run closed: plain store
                    outp[(size_t)rA * 128 + lane] = a * OSCALE;
                    a = 0.f; rA = rc;
                }
                a += st[lane][ee];                      // stride-65: conflict-free
            }
            accA = a;
        }
        __syncthreads();

        // ---- chunk 1: channels 64..127 = oV(32..95) ----
#pragma unroll
        for (int j = 0; j < 64; ++j) st[j][lane] = oV[32 + j];
        __syncthreads();
        {
            int rB = rprev; float b = accB;
            for (int ee = 0; ee < nv; ++ee) {
                const int rc = rcvt[ee];
                if (rc != rB) {
                    outp[(size_t)rB * 128 + 64 + lane] = b * OSCALE;
                    b = 0.f; rB = rc;
                }
                b += st[lane][ee];
            }
            accB = b; rprev = rB;
        }
        __syncthreads();                                // protect st/rcvt for next batch
    }

    // final (still-open) run
    outp[(size_t)rprev * 128 + lane]      = accA * OSCALE;
    outp[(size_t)rprev * 128 + 64 + lane] = accB * OSCALE;
}

extern "C" void kernel_launch(void* const* d_in, const int* in_sizes, int n_in,
                              void* d_out, int out_size, void* d_ws, size_t ws_size,
                              hipStream_t stream) {
    const float* node_feats = (const float*)d_in[0];
    const float* edge_vec   = (const float*)d_in[1];
    const float* edge_len   = (const float*)d_in[2];
    const int*   senders    = (const int*)d_in[3];
    const int*   receivers  = (const int*)d_in[4];
    const float* W_up0  = (const float*)d_in[6];
    const float* W_up1  = (const float*)d_in[7];
    const float* mlp_w0 = (const float*)d_in[8];
    const float* mlp_b0 = (const float*)d_in[9];
    const float* mlp_w1 = (const float*)d_in[10];
    const float* mlp_b1 = (const float*)d_in[11];
    const float* mlp_w2 = (const float*)d_in[12];
    const float* mlp_b2 = (const float*)d_in[13];
    const float* W_out0 = (const float*)d_in[14];
    const float* W_out1 = (const float*)d_in[15];

    const int N  = in_sizes[0] / 128;
    const int E  = in_sizes[1] / 3;
    const int NW = (E + 63) / 64;

    // workspace layout (~30 MB)
    float* xall = (float*)d_ws;                        // N*128 f32 (25.6 MB)
    float* w2t  = xall + (size_t)N * 128;              // 8192 f32
    int*   cnt  = (int*)(w2t + 8192);                  // N
    int*   off  = cnt + N;                             // N+1
    int*   cur  = off + N + 1;                         // N
    int*   sid  = cur + N;                             // E
    int*   wlo  = sid + E;                             // NW
    int*   whi  = wlo + NW;                            // NW

    tr_kernel<<<32, 256, 0, stream>>>(mlp_w2, w2t);
    up_kernel<<<(N * 32 + 255) / 256, 256, 0, stream>>>(node_feats, W_up0, W_up1, xall, N);

    // CSR sort by receiver
    hipMemsetAsync(cnt, 0, (size_t)(3 * N + 1) * sizeof(int), stream);
    hist_kernel<<<(E + 255) / 256, 256, 0, stream>>>(receivers, cnt, E);
    scan_kernel<<<1, 1024, 0, stream>>>(cnt, off, N, E);
    scat_kernel<<<(E + 255) / 256, 256, 0, stream>>>(receivers, off, cur, sid, E);

    // wave -> node ownership
    hipMemsetAsync(wlo, 0x7f, (size_t)NW * sizeof(int), stream);
    hipMemsetAsync(whi, 0xff, (size_t)NW * sizeof(int), stream);
    wassign_kernel<<<(N + 255) / 256, 256, 0, stream>>>(off, wlo, whi, N, NW);

    hipMemsetAsync(d_out, 0, (size_t)out_size * sizeof(float), stream);
    ek5<<<NW, 64, 0, stream>>>(edge_vec, edge_len, senders, receivers, sid, off,
                               wlo, whi,
                               mlp_w0, mlp_b0, mlp_w1, mlp_b1, mlp_b2,
                               w2t, W_out0, W_out1,
                               (const float4*)xall, (float*)d_out, E);
}

// Round 16
// 3111.483 us; speedup vs baseline: 1.0521x; 1.0521x over previous
//
#include <hip/hip_runtime.h>
#include <math.h>

#define SQ3F   1.7320508075688772f
#define SQRT8F 2.8284271247461903f
#define OSCALE (1.0f / 128.0f)   // (1/sqrt(64)) * (1/AVG=16)

__device__ __forceinline__ float fast_silu(float x) {
    return x * __builtin_amdgcn_rcpf(1.0f + __expf(-x));
}

// ---------------------------------------------------------------- transpose w2
__global__ __launch_bounds__(256) void tr_kernel(const float* __restrict__ w2,
                                                 float* __restrict__ w2t) {
    const int t = blockIdx.x * 256 + threadIdx.x;   // 8192 = 128 x 64
    if (t < 8192) {
        const int o = t >> 6, i = t & 63;
        w2t[t] = w2[i * 128 + o];                   // w2t[o][i] = w2[i][o]
    }
}

// ---------------------------------------------------------------- up-projection
// xall[n][m] = float4{ xs[n][m], xv[n][m][0], xv[n][m][1], xv[n][m][2] }
__global__ __launch_bounds__(256) void up_kernel(const float* __restrict__ nf,
                                                 const float* __restrict__ Wu0,
                                                 const float* __restrict__ Wu1,
                                                 float* __restrict__ xall, int N) {
    __shared__ float sW0[1024], sW1[1024];
    for (int i = threadIdx.x; i < 1024; i += 256) { sW0[i] = Wu0[i]; sW1[i] = Wu1[i]; }
    __syncthreads();
    const int t = blockIdx.x * 256 + threadIdx.x;
    const int n = t >> 5, k = t & 31;
    if (n >= N) return;
    const float* row = nf + (size_t)n * 128;
    float a0 = 0.f, a1 = 0.f, a2 = 0.f, a3 = 0.f;
#pragma unroll
    for (int m = 0; m < 32; ++m) {
        const float wa = sW0[m * 32 + k], wb = sW1[m * 32 + k];
        a0 += row[m] * wa;
        a1 += row[32 + m * 3 + 0] * wb;
        a2 += row[32 + m * 3 + 1] * wb;
        a3 += row[32 + m * 3 + 2] * wb;
    }
    const float s = 0.17677669529663687f;  // 1/sqrt(32)
    float4 o; o.x = a0 * s; o.y = a1 * s; o.z = a2 * s; o.w = a3 * s;
    reinterpret_cast<float4*>(xall)[(size_t)n * 32 + k] = o;
}

// ---------------------------------------------------------------- CSR build
__global__ __launch_bounds__(256) void hist_kernel(const int* __restrict__ rcv,
                                                   int* __restrict__ cnt, int E) {
    const int t = blockIdx.x * 256 + threadIdx.x;
    if (t < E) atomicAdd(&cnt[rcv[t]], 1);
}

__global__ __launch_bounds__(1024) void scan_kernel(const int* __restrict__ cnt,
                                                    int* __restrict__ off, int N, int E) {
    __shared__ int part[1024];
    const int t = threadIdx.x;
    const int CH = (N + 1023) / 1024;
    const int lo = t * CH;
    const int hi = (lo + CH < N) ? lo + CH : N;
    int s = 0;
    for (int i = lo; i < hi; ++i) s += cnt[i];
    part[t] = s;
    __syncthreads();
    for (int d = 1; d < 1024; d <<= 1) {
        const int v = (t >= d) ? part[t - d] : 0;
        __syncthreads();
        part[t] += v;
        __syncthreads();
    }
    int run = (t > 0) ? part[t - 1] : 0;
    for (int i = lo; i < hi; ++i) { off[i] = run; run += cnt[i]; }
    if (t == 0) off[N] = E;
}

__global__ __launch_bounds__(256) void scat_kernel(const int* __restrict__ rcv,
                                                   const int* __restrict__ off,
                                                   int* __restrict__ cur,
                                                   int* __restrict__ sid, int E) {
    const int t = blockIdx.x * 256 + threadIdx.x;
    if (t < E) {
        const int r = rcv[t];
        const int p = off[r] + atomicAdd(&cur[r], 1);
        sid[p] = t;
    }
}

// ---------------------------------------------------------------- wave->node assignment
__global__ __launch_bounds__(256) void wassign_kernel(const int* __restrict__ off,
                                                      int* __restrict__ wlo,
                                                      int* __restrict__ whi,
                                                      int N, int NW) {
    const int n = blockIdx.x * 256 + threadIdx.x;
    if (n < N) {
        int w = off[n] >> 6;
        if (w >= NW) w = NW - 1;
        atomicMin(&wlo[w], n);
        atomicMax(&whi[w], n);
    }
}

// ---------------------------------------------------------------- edge kernel v6
// Single merged m-loop, h1 in registers, tA folded inline (t1*Yc) to cap peak
// live VGPRs at ~215. amdgpu_waves_per_eu(2,2) pins allocator to the 256-VGPR
// budget (occupancy is LDS-capped near 2 waves/EU anyway) -> NO scratch spill,
// NO LDS in the hot loop. Output path identical to proven ek4.
__global__ __launch_bounds__(64) __attribute__((amdgpu_waves_per_eu(2, 2)))
void ek6(const float* __restrict__ edge_vec,
         const float* __restrict__ edge_len,
         const int*  __restrict__ senders,
         const int*  __restrict__ receivers,
         const int*  __restrict__ sid,
         const int*  __restrict__ off,
         const int*  __restrict__ wlo,
         const int*  __restrict__ whi,
         const float* __restrict__ w0,   // (8,64)
         const float* __restrict__ b0,   // 64
         const float* __restrict__ w1,   // (64,64)
         const float* __restrict__ b1,   // 64
         const float* __restrict__ b2,   // 128
         const float* __restrict__ w2t,  // (128,64)
         const float* __restrict__ Wo0,  // (64,32)
         const float* __restrict__ Wo1,  // (64,32)
         const float4* __restrict__ xall,
         float* __restrict__ outp,       // N x 128 (zeroed)
         int E) {
    __shared__ float st[64][65];                    // restage only (16.6 KiB)
    __shared__ int   rcvt[64];
    const int lane = threadIdx.x;
    const int w = blockIdx.x;
    const int nlo = wlo[w], nhi = whi[w];
    if (nhi < nlo) return;
    const int estart = off[nlo], eend = off[nhi + 1];
    if (estart >= eend) return;

    int   rprev = -1;
    float accA = 0.f, accB = 0.f;

    for (int bs = estart; bs < eend; bs += 64) {
        const int nv = (eend - bs < 64) ? (eend - bs) : 64;   // wave-uniform
        const int sp = (lane < nv) ? (bs + lane) : (eend - 1);
        const int e  = sid[sp];
        rcvt[lane] = receivers[e];

        const float ev0 = edge_vec[e * 3 + 0];
        const float ev1 = edge_vec[e * 3 + 1];
        const float ev2 = edge_vec[e * 3 + 2];
        const float r   = edge_len[e];
        const int  snd  = senders[e];

        const float nrm = sqrtf(ev0 * ev0 + ev1 * ev1 + ev2 * ev2) + 1e-12f;
        const float sc  = SQ3F * __builtin_amdgcn_rcpf(nrm);
        const float Y0 = ev0 * sc, Y1 = ev1 * sc, Y2 = ev2 * sc;

        const float xcl  = fminf(fmaxf(r, 0.0f), 1.0f);
        const float gate = (r <= 1.0f) ? SQRT8F : 0.0f;
        float emb[8];
#pragma unroll
        for (int i = 0; i < 8; ++i) {
            const float d = xcl * 7.0f - (float)i;
            emb[i] = __expf(-0.5f * d * d) * gate;
        }

        // layer 1: 8 -> 64, h0 in regs (static unroll)
        float h0[64];
#pragma unroll
        for (int o = 0; o < 64; ++o) {
            float a = b0[o];
#pragma unroll
            for (int i = 0; i < 8; ++i) a += emb[i] * w0[i * 64 + o];
            h0[o] = fast_silu(a);
        }

        // layer 2: 64 -> 64, h1 in regs (ob fully unrolled -> static indices)
        float h1[64];
#pragma unroll
        for (int ob = 0; ob < 64; ob += 8) {
            float a[8];
#pragma unroll
            for (int u = 0; u < 8; ++u) a[u] = b1[ob + u];
#pragma unroll
            for (int i = 0; i < 64; ++i) {
                const float hv = h0[i];
#pragma unroll
                for (int u = 0; u < 8; ++u) a[u] += hv * w1[i * 64 + ob + u];
            }
#pragma unroll
            for (int u = 0; u < 8; ++u) h1[ob + u] = fast_silu(a[u]);
        }
        // h0 dead from here

        // ---- single-pass layer 3 + message + W_out contraction ----
        const float4* xrow = xall + (size_t)snd * 32;
        float outS[32], oV[96];
#pragma unroll
        for (int k = 0; k < 32; ++k) outS[k] = 0.f;
#pragma unroll
        for (int k = 0; k < 96; ++k) oV[k] = 0.f;

#pragma unroll 1
        for (int m = 0; m < 32; ++m) {
            const float* r0 = w2t + m * 64;
            const float* r1 = w2t + (32 + m) * 64;
            const float* r2 = w2t + (64 + m) * 64;
            const float* r3 = w2t + (96 + m) * 64;
            float d0 = b2[m], d1 = b2[32 + m], d2 = b2[64 + m], d3 = b2[96 + m];
#pragma unroll
            for (int i = 0; i < 64; ++i) {
                const float hv = h1[i];
                d0 += hv * r0[i]; d1 += hv * r1[i];
                d2 += hv * r2[i]; d3 += hv * r3[i];
            }
            const float4 g = xrow[m];
            const float ss = g.x;
            const float dv = g.y * Y0 + g.z * Y1 + g.w * Y2;
            const float a0 = d0 * ss;                   // m0[m]
            const float a3 = d3 * dv * (1.0f / SQ3F);   // m3[m]
            const float t1 = d1 * ss;                   // m1[m] coefficient of Y
            const float t1Y0 = t1 * Y0, t1Y1 = t1 * Y1, t1Y2 = t1 * Y2;
            const float p0 = d2 * g.y, p1 = d2 * g.z, p2 = d2 * g.w;  // m2[m][c]
            const float* wa = Wo0 + m * 32;
            const float* wb = Wo0 + (32 + m) * 32;
            const float* wc = Wo1 + m * 32;
            const float* wd = Wo1 + (32 + m) * 32;
#pragma unroll
            for (int k = 0; k < 32; ++k) {
                outS[k] += a0 * wa[k] + a3 * wb[k];
                const float wcv = wc[k], wdv = wd[k];
                oV[k * 3 + 0] += t1Y0 * wcv + p0 * wdv;
                oV[k * 3 + 1] += t1Y1 * wcv + p1 * wdv;
                oV[k * 3 + 2] += t1Y2 * wcv + p2 * wdv;
            }
        }

        // ---- chunk 0: channels 0..63 = [outS(32) | oV(0..31)] ----
        __syncthreads();                               // st free (prev batch done)
#pragma unroll
        for (int j = 0; j < 32; ++j) st[j][lane]      = outS[j];
#pragma unroll
        for (int j = 0; j < 32; ++j) st[32 + j][lane] = oV[j];
        __syncthreads();
        if (rprev < 0) rprev = rcvt[0];
        {
            int rA = rprev; float a = accA;
            for (int ee = 0; ee < nv; ++ee) {
                const int rc = rcvt[ee];                // wave-uniform
                if (rc != rA) {                         // run closed: plain store
                    outp[(size_t)rA * 128 + lane] = a * OSCALE;
                    a = 0.f; rA = rc;
                }
                a += st[lane][ee];                      // stride-65: conflict-free
            }
            accA = a;
        }
        __syncthreads();

        // ---- chunk 1: channels 64..127 = oV(32..95) ----
#pragma unroll
        for (int j = 0; j < 64; ++j) st[j][lane] = oV[32 + j];
        __syncthreads();
        {
            int rB = rprev; float b = accB;
            for (int ee = 0; ee < nv; ++ee) {
                const int rc = rcvt[ee];
                if (rc != rB) {
                    outp[(size_t)rB * 128 + 64 + lane] = b * OSCALE;
                    b = 0.f; rB = rc;
                }
                b += st[lane][ee];
            }
            accB = b; rprev = rB;
        }
        __syncthreads();                                // protect st/rcvt for next batch
    }

    // final (still-open) run
    outp[(size_t)rprev * 128 + lane]      = accA * OSCALE;
    outp[(size_t)rprev * 128 + 64 + lane] = accB * OSCALE;
}

extern "C" void kernel_launch(void* const* d_in, const int* in_sizes, int n_in,
                              void* d_out, int out_size, void* d_ws, size_t ws_size,
                              hipStream_t stream) {
    const float* node_feats = (const float*)d_in[0];
    const float* edge_vec   = (const float*)d_in[1];
    const float* edge_len   = (const float*)d_in[2];
    const int*   senders    = (const int*)d_in[3];
    const int*   receivers  = (const int*)d_in[4];
    const float* W_up0  = (const float*)d_in[6];
    const float* W_up1  = (const float*)d_in[7];
    const float* mlp_w0 = (const float*)d_in[8];
    const float* mlp_b0 = (const float*)d_in[9];
    const float* mlp_w1 = (const float*)d_in[10];
    const float* mlp_b1 = (const float*)d_in[11];
    const float* mlp_w2 = (const float*)d_in[12];
    const float* mlp_b2 = (const float*)d_in[13];
    const float* W_out0 = (const float*)d_in[14];
    const float* W_out1 = (const float*)d_in[15];

    const int N  = in_sizes[0] / 128;
    const int E  = in_sizes[1] / 3;
    const int NW = (E + 63) / 64;

    // workspace layout (~30 MB)
    float* xall = (float*)d_ws;                        // N*128 f32 (25.6 MB)
    float* w2t  = xall + (size_t)N * 128;              // 8192 f32
    int*   cnt  = (int*)(w2t + 8192);                  // N
    int*   off  = cnt + N;                             // N+1
    int*   cur  = off + N + 1;                         // N
    int*   sid  = cur + N;                             // E
    int*   wlo  = sid + E;                             // NW
    int*   whi  = wlo + NW;                            // NW

    tr_kernel<<<32, 256, 0, stream>>>(mlp_w2, w2t);
    up_kernel<<<(N * 32 + 255) / 256, 256, 0, stream>>>(node_feats, W_up0, W_up1, xall, N);

    // CSR sort by receiver
    hipMemsetAsync(cnt, 0, (size_t)(3 * N + 1) * sizeof(int), stream);
    hist_kernel<<<(E + 255) / 256, 256, 0, stream>>>(receivers, cnt, E);
    scan_kernel<<<1, 1024, 0, stream>>>(cnt, off, N, E);
    scat_kernel<<<(E + 255) / 256, 256, 0, stream>>>(receivers, off, cur, sid, E);

    // wave -> node ownership
    hipMemsetAsync(wlo, 0x7f, (size_t)NW * sizeof(int), stream);
    hipMemsetAsync(whi, 0xff, (size_t)NW * sizeof(int), stream);
    wassign_kernel<<<(N + 255) / 256, 256, 0, stream>>>(off, wlo, whi, N, NW);

    hipMemsetAsync(d_out, 0, (size_t)out_size * sizeof(float), stream);
    ek6<<<NW, 64, 0, stream>>>(edge_vec, edge_len, senders, receivers, sid, off,
                               wlo, whi,
                               mlp_w0, mlp_b0, mlp_w1, mlp_b1, mlp_b2,
                               w2t, W_out0, W_out1,
                               (const float4*)xall, (float*)d_out, E);
}